// Round 3
// baseline (258.637 us; speedup 1.0000x reference)
//
#include <hip/hip_runtime.h>

// WHXE loss, round 3: full-batch loads (16 independent float4s in flight) +
// fused epilogue via last-block reduction (2 dispatches total).
//   colS[n] = sum_b lam[n] * logp[b,n] * true[b,n]
//   cnt[n]  = sum_b true[b,n]
//   loss    = -(1/B) * sum_n (B / (N*(cnt[n]+eps))) * colS[n]
// Sibling groups are 4 consecutive columns (group_ids = repeat(arange(32),4)),
// so one float4 load = one complete softmax group.

#define B_TOTAL 131072
#define N_NODES 128
#define ALPHA   0.5f
#define EPS     1e-10f

constexpr int BLOCKS         = 2048;
constexpr int THREADS        = 256;
constexpr int ROWS_PER_ITER  = THREADS / 32;                    // 8
constexpr int ROWS_PER_BLOCK = B_TOTAL / BLOCKS;                // 64
constexpr int ITERS          = ROWS_PER_BLOCK / ROWS_PER_ITER;  // 8 (compile-time)
constexpr int REPLICAS       = 32;   // replica r only touched by blocks == r (mod 32)
                                     // -> single XCD per replica line (blockIdx&7 fixed)

__global__ __launch_bounds__(THREADS) void whxe_fused(
    const float* __restrict__ logits,
    const float* __restrict__ truev,
    const float* __restrict__ depths,
    float* __restrict__ ws,          // [REPLICAS*256] accum, then 1 uint done-ctr
    float* __restrict__ out)
{
    const int t    = threadIdx.x;
    const int cg   = t & 31;          // column group 0..31 (4 cols each)
    const int rsub = t >> 5;          // row-within-iteration 0..7
    const int c0   = cg << 2;

    float lam[4];
#pragma unroll
    for (int i = 0; i < 4; ++i) lam[i] = __expf(-ALPHA * depths[c0 + i]);

    const size_t base0 = (size_t)(blockIdx.x * ROWS_PER_BLOCK + rsub) * N_NODES + c0;
    const float* lp = logits + base0;
    const float* tp = truev  + base0;
    constexpr size_t STRIDE = (size_t)ROWS_PER_ITER * N_NODES;  // 1024 elems

    // all 16 loads issued before any use: max memory-level parallelism
    float4 xa[ITERS], ta[ITERS];
#pragma unroll
    for (int it = 0; it < ITERS; ++it) {
        xa[it] = *reinterpret_cast<const float4*>(lp + (size_t)it * STRIDE);
        ta[it] = *reinterpret_cast<const float4*>(tp + (size_t)it * STRIDE);
    }

    float colS[4] = {0.f, 0.f, 0.f, 0.f};
    float cnt [4] = {0.f, 0.f, 0.f, 0.f};
#pragma unroll
    for (int it = 0; it < ITERS; ++it) {
        const float4 x  = xa[it];
        const float4 tv = ta[it];
        const float e0 = __expf(x.x), e1 = __expf(x.y),
                    e2 = __expf(x.z), e3 = __expf(x.w);
        const float ld = __logf(e0 + e1 + e2 + e3 + EPS);
        colS[0] += lam[0] * (x.x - ld) * tv.x;  cnt[0] += tv.x;
        colS[1] += lam[1] * (x.y - ld) * tv.y;  cnt[1] += tv.y;
        colS[2] += lam[2] * (x.z - ld) * tv.z;  cnt[2] += tv.z;
        colS[3] += lam[3] * (x.w - ld) * tv.w;  cnt[3] += tv.w;
    }

    // block reduction: 8 accumulators/thread -> 256 partials
    __shared__ float lds[8][THREADS];
#pragma unroll
    for (int i = 0; i < 4; ++i) {
        lds[i][t]     = colS[i];
        lds[4 + i][t] = cnt[i];
    }
    __syncthreads();

    const int q   = t >> 7;           // 0 = colS, 1 = cnt
    const int c   = t & 127;          // column
    const int acc = q * 4 + (c & 3);
    const int cgr = c >> 2;
    float s = 0.f;
#pragma unroll
    for (int r = 0; r < 8; ++r) s += lds[acc][r * 32 + cgr];

    const int rep = blockIdx.x & (REPLICAS - 1);
    atomicAdd(&ws[rep * 256 + q * 128 + c], s);   // device-scope by default

    // ---- completion detection: last block folds the 32 replicas ----
    unsigned int* done = (unsigned int*)(ws + REPLICAS * 256);
    __shared__ bool last;
    __threadfence();                  // my atomic is at the coherence point
    __syncthreads();                  // whole block done
    if (t == 0) last = (atomicAdd(done, 1u) == (unsigned)(BLOCKS - 1));
    __syncthreads();
    if (!last) return;

    __threadfence();                  // acquire
    float fs = 0.f;
#pragma unroll
    for (int r = 0; r < REPLICAS; ++r)
        fs += __hip_atomic_load(&ws[r * 256 + t], __ATOMIC_RELAXED,
                                __HIP_MEMORY_SCOPE_AGENT);
    __shared__ float red[256];
    red[t] = fs;
    __syncthreads();

    if (t < 64) {
        float v = 0.f;
#pragma unroll
        for (int cc = t; cc < 128; cc += 64) {
            const float w = (float)B_TOTAL / ((float)N_NODES * (red[128 + cc] + EPS));
            v += w * red[cc];
        }
#pragma unroll
        for (int off = 32; off; off >>= 1) v += __shfl_xor(v, off);
        if (t == 0) out[0] = -v / (float)B_TOTAL;
    }
}

extern "C" void kernel_launch(void* const* d_in, const int* in_sizes, int n_in,
                              void* d_out, int out_size, void* d_ws, size_t ws_size,
                              hipStream_t stream) {
    const float* logits = (const float*)d_in[0];
    const float* truev  = (const float*)d_in[1];
    const float* depths = (const float*)d_in[2];
    float* ws = (float*)d_ws;

    hipMemsetAsync(ws, 0, REPLICAS * 256 * sizeof(float) + sizeof(unsigned int),
                   stream);
    whxe_fused<<<BLOCKS, THREADS, 0, stream>>>(logits, truev, depths, ws,
                                               (float*)d_out);
}

// Round 4
// 32.507 us; speedup vs baseline: 7.9565x; 7.9565x over previous
//
#include <hip/hip_runtime.h>

// WHXE loss, round 4: back to the proven 3-dispatch structure (R2, no fences),
// with REAL load batching: 8 loads clustered per group, pinned by
// sched_barrier(0) so the compiler cannot sink them into the compute.
//   colS[n] = sum_b lam[n] * logp[b,n] * true[b,n]
//   cnt[n]  = sum_b true[b,n]
//   loss    = -(1/B) * sum_n (B / (N*(cnt[n]+eps))) * colS[n]
// Sibling groups are 4 consecutive columns (group_ids = repeat(arange(32),4)),
// so one float4 load = one complete softmax group.
// LESSON (R3): never put a device-scope __threadfence() in every block on
// gfx950 — it forces per-XCD L2 writeback/invalidate and serialized the chip.

#define B_TOTAL 131072
#define N_NODES 128
#define ALPHA   0.5f
#define EPS     1e-10f

constexpr int BLOCKS         = 2048;
constexpr int THREADS        = 256;
constexpr int ROWS_PER_ITER  = THREADS / 32;                    // 8
constexpr int ROWS_PER_BLOCK = B_TOTAL / BLOCKS;                // 64
constexpr int ITERS          = ROWS_PER_BLOCK / ROWS_PER_ITER;  // 8 (compile-time)
constexpr int BATCH          = 4;                               // row-iters per load batch
constexpr int NBATCH         = ITERS / BATCH;                   // 2
constexpr int REPLICAS       = 32;

__global__ __launch_bounds__(THREADS, 8) void whxe_pass1(
    const float* __restrict__ logits,
    const float* __restrict__ truev,
    const float* __restrict__ depths,
    float* __restrict__ ws)   // ws[rep][256]: [0..127]=colS, [128..255]=cnt
{
    const int t    = threadIdx.x;
    const int cg   = t & 31;          // column group 0..31 (4 cols each)
    const int rsub = t >> 5;          // row-within-iteration 0..7
    const int c0   = cg << 2;

    float lam[4];
#pragma unroll
    for (int i = 0; i < 4; ++i) lam[i] = __expf(-ALPHA * depths[c0 + i]);

    const size_t base0 = (size_t)(blockIdx.x * ROWS_PER_BLOCK + rsub) * N_NODES + c0;
    const float* lp = logits + base0;
    const float* tp = truev  + base0;
    constexpr size_t STRIDE = (size_t)ROWS_PER_ITER * N_NODES;  // 1024 elems

    float colS[4] = {0.f, 0.f, 0.f, 0.f};
    float cnt [4] = {0.f, 0.f, 0.f, 0.f};

#pragma unroll
    for (int g = 0; g < NBATCH; ++g) {
        // --- load cluster: 8 independent float4 loads in flight (8 KB/wave) ---
        float4 x[BATCH], tv[BATCH];
#pragma unroll
        for (int i = 0; i < BATCH; ++i) {
            const size_t off = (size_t)(g * BATCH + i) * STRIDE;
            x [i] = *reinterpret_cast<const float4*>(lp + off);
            tv[i] = *reinterpret_cast<const float4*>(tp + off);
        }
        __builtin_amdgcn_sched_barrier(0);   // do NOT sink loads into compute
        // --- compute cluster ---
#pragma unroll
        for (int i = 0; i < BATCH; ++i) {
            const float e0 = __expf(x[i].x), e1 = __expf(x[i].y),
                        e2 = __expf(x[i].z), e3 = __expf(x[i].w);
            const float ld = __logf(e0 + e1 + e2 + e3 + EPS);
            colS[0] += lam[0] * (x[i].x - ld) * tv[i].x;  cnt[0] += tv[i].x;
            colS[1] += lam[1] * (x[i].y - ld) * tv[i].y;  cnt[1] += tv[i].y;
            colS[2] += lam[2] * (x[i].z - ld) * tv[i].z;  cnt[2] += tv[i].z;
            colS[3] += lam[3] * (x[i].w - ld) * tv[i].w;  cnt[3] += tv[i].w;
        }
    }

    // block reduction: 8 accumulators/thread -> 256 partials
    __shared__ float lds[8][THREADS];
#pragma unroll
    for (int i = 0; i < 4; ++i) {
        lds[i][t]     = colS[i];
        lds[4 + i][t] = cnt[i];
    }
    __syncthreads();

    const int q   = t >> 7;           // 0 = colS, 1 = cnt
    const int c   = t & 127;          // column
    const int acc = q * 4 + (c & 3);
    const int cgr = c >> 2;
    float s = 0.f;
#pragma unroll
    for (int r = 0; r < 8; ++r) s += lds[acc][r * 32 + cgr];

    // replica-spread atomics: 64 adds per address (no fence needed; atomicAdd
    // is device-scope at the coherence point)
    const int rep = blockIdx.x & (REPLICAS - 1);
    atomicAdd(&ws[rep * 256 + q * 128 + c], s);
}

__global__ __launch_bounds__(256) void whxe_pass2(
    const float* __restrict__ ws, float* __restrict__ out)
{
    const int t = threadIdx.x;        // 256
    float s = 0.f;
#pragma unroll
    for (int r = 0; r < REPLICAS; ++r) s += ws[r * 256 + t];

    __shared__ float red[256];
    red[t] = s;
    __syncthreads();

    if (t < 64) {
        float v = 0.f;
#pragma unroll
        for (int cc = t; cc < 128; cc += 64) {
            const float w = (float)B_TOTAL / ((float)N_NODES * (red[128 + cc] + EPS));
            v += w * red[cc];
        }
#pragma unroll
        for (int off = 32; off; off >>= 1) v += __shfl_xor(v, off);
        if (t == 0) out[0] = -v / (float)B_TOTAL;
    }
}

extern "C" void kernel_launch(void* const* d_in, const int* in_sizes, int n_in,
                              void* d_out, int out_size, void* d_ws, size_t ws_size,
                              hipStream_t stream) {
    const float* logits = (const float*)d_in[0];
    const float* truev  = (const float*)d_in[1];
    const float* depths = (const float*)d_in[2];
    float* ws = (float*)d_ws;

    hipMemsetAsync(ws, 0, REPLICAS * 256 * sizeof(float), stream);
    whxe_pass1<<<BLOCKS, THREADS, 0, stream>>>(logits, truev, depths, ws);
    whxe_pass2<<<1, 256, 0, stream>>>(ws, (float*)d_out);
}